// Round 7
// baseline (28316.547 us; speedup 1.0000x reference)
//
#include <hip/hip_runtime.h>
#include <cmath>

#define SEQ 4096
#define INP 457
#define EMB 2048
#define NWG_E 256   // encoder: 1 WG (512 thr) per CU; weights pinned in VGPRs
#define NWG_D 16    // decoder: 16 WGs x 32 c-indices = 512 >= 457
#define NMIR 8      // enc broadcast mirrors (readers/line 256 -> 32)

typedef unsigned long long u64t;

__device__ __forceinline__ float sigf(float v) { return 1.0f / (1.0f + expf(-v)); }

// Opaque pin: value becomes output of an opaque asm -> compiler cannot rematerialize
#define PIN(v) asm volatile("" : "+v"(v))

#define ALD(p)    __hip_atomic_load((p), __ATOMIC_RELAXED, __HIP_MEMORY_SCOPE_AGENT)
#define AST(p, v) __hip_atomic_store((p), (v), __ATOMIC_RELAXED, __HIP_MEMORY_SCOPE_AGENT)

__device__ __forceinline__ float    loF(u64t p) { return __builtin_bit_cast(float, (unsigned)p); }
__device__ __forceinline__ unsigned hiT(u64t p) { return (unsigned)(p >> 32); }
__device__ __forceinline__ u64t packFT(float v, unsigned tag) {
  return ((u64t)tag << 32) | (u64t)__builtin_bit_cast(unsigned, v);
}

// ---------------- bias precompute ----------------
__global__ void bias_kernel(const float* __restrict__ ebih, const float* __restrict__ ebhh,
                            const float* __restrict__ dbih, const float* __restrict__ dbhh,
                            float* __restrict__ bsum, float* __restrict__ btot) {
  int i = blockIdx.x * 256 + threadIdx.x;
  if (i < 4 * EMB) bsum[i] = ebih[i] + ebhh[i];
  if (i < 4 * INP) btot[i] = dbih[i] + dbhh[i];
}

// ---------------- Wfold = (dec_Wih + dec_Whh) @ dec_Whr  (1828 x 480, pad cols zero) ----------------
__global__ __launch_bounds__(256) void fold_gemm(const float* __restrict__ dWih,
                                                 const float* __restrict__ dWhh,
                                                 const float* __restrict__ dWhr,
                                                 float* __restrict__ C) {
  const int bx = blockIdx.x, by = blockIdx.y;
  const int tid = threadIdx.x;
  const int tx = tid & 15, ty = tid >> 4;
  __shared__ float As[16][65];
  __shared__ float Bs[16][65];
  float acc[4][4] = {};
  for (int k0 = 0; k0 < EMB; k0 += 16) {
#pragma unroll
    for (int e = 0; e < 4; ++e) {
      int eid = tid * 4 + e;
      int m = eid >> 4, k = eid & 15;
      int row = by * 64 + m;
      float v = 0.0f;
      if (row < 4 * INP) {
        size_t a = (size_t)row * EMB + k0 + k;
        v = dWih[a] + dWhh[a];
      }
      As[k][m] = v;
    }
#pragma unroll
    for (int e = 0; e < 4; ++e) {
      int eid = tid * 4 + e;
      int k = eid >> 6, c = eid & 63;
      int col = bx * 64 + c;
      Bs[k][c] = (col < INP) ? dWhr[(size_t)(k0 + k) * INP + col] : 0.0f;
    }
    __syncthreads();
#pragma unroll
    for (int k = 0; k < 16; ++k) {
      float a0 = As[k][ty * 4 + 0], a1 = As[k][ty * 4 + 1], a2 = As[k][ty * 4 + 2], a3 = As[k][ty * 4 + 3];
      float b0 = Bs[k][tx * 4 + 0], b1 = Bs[k][tx * 4 + 1], b2 = Bs[k][tx * 4 + 2], b3 = Bs[k][tx * 4 + 3];
      acc[0][0] += a0 * b0; acc[0][1] += a0 * b1; acc[0][2] += a0 * b2; acc[0][3] += a0 * b3;
      acc[1][0] += a1 * b0; acc[1][1] += a1 * b1; acc[1][2] += a1 * b2; acc[1][3] += a1 * b3;
      acc[2][0] += a2 * b0; acc[2][1] += a2 * b1; acc[2][2] += a2 * b2; acc[2][3] += a2 * b3;
      acc[3][0] += a3 * b0; acc[3][1] += a3 * b1; acc[3][2] += a3 * b2; acc[3][3] += a3 * b3;
    }
    __syncthreads();
  }
#pragma unroll
  for (int i = 0; i < 4; ++i) {
    int row = by * 64 + ty * 4 + i;
    if (row >= 4 * INP) continue;
#pragma unroll
    for (int j = 0; j < 4; ++j) {
      int col = bx * 64 + tx * 4 + j;
      if (col < 480) C[(size_t)row * 480 + col] = acc[i][j];
    }
  }
}

// ---------------- persistent encoder: 8-way mirrors + 3-deep pipelined tag-poll ----------------
// 256 WGs x 512 thr. WG w owns h[8w..8w+8). Thread: j=tid&7, kc=tid>>3, wave wv=tid>>6.
// Wave wv consumes h[256wv..256wv+256) as tagged u64 (float val | u32 step-tag) from
// mirror (wg&7). Poll wake-granularity cut ~3x by keeping 3 staggered load-sets in
// flight (vmcnt-throttled; no s_sleep) - the poll path is HBM-latency (r6 FETCH~WRITE).
// Race-freedom (unchanged): tag travels with value in one u64; a producer overwrites
// slot t with tag t+2 only after observing ALL 256 WGs' t+1 tags -> no future tags seen.
__global__ __launch_bounds__(512) __attribute__((amdgpu_waves_per_eu(2, 2))) void enc_kernel(
    const float* __restrict__ x, const float* __restrict__ Wih,
    const float* __restrict__ Whh, const float* __restrict__ bsum,
    u64t* __restrict__ hbuf, float* __restrict__ hencbuf) {
  const int tid  = threadIdx.x;
  const int wg   = blockIdx.x;
  const int j    = tid & 7;
  const int kc   = tid >> 3;   // 0..63 global k-chunk
  const int wv   = tid >> 6;   // 0..7
  const int lane = tid & 63;
  const int kcL  = kc & 7;     // k-chunk within wave
  const int jbase = wg * 8;
  const int mir  = wg & (NMIR - 1);

  float wh[4][32];
  float wi[4][8];
#pragma unroll
  for (int g = 0; g < 4; ++g) {
    const size_t row = (size_t)(g * EMB + jbase + j);
    const float* wp = Whh + row * EMB + kc * 32;
#pragma unroll
    for (int q = 0; q < 8; ++q) {
      const float4 v = *(const float4*)(wp + 4 * q);
      wh[g][q * 4 + 0] = v.x; wh[g][q * 4 + 1] = v.y;
      wh[g][q * 4 + 2] = v.z; wh[g][q * 4 + 3] = v.w;
    }
    const float* ip = Wih + row * INP;
#pragma unroll
    for (int i = 0; i < 8; ++i) {
      const int c = kc * 8 + i;
      wi[g][i] = (c < INP) ? ip[c] : 0.0f;
    }
  }
#pragma unroll
  for (int g = 0; g < 4; ++g) {
#pragma unroll
    for (int q = 0; q < 32; ++q) PIN(wh[g][q]);
#pragma unroll
    for (int q = 0; q < 8; ++q) PIN(wi[g][q]);
  }

  __shared__ float4 hl4[8][64];          // per-wave h granules (XOR-swizzled within wave)
  __shared__ float  xs[8][64];           // per-wave x slice
  __shared__ float  partbuf[2][8][8][4]; // parity x wave x j x gate
  __shared__ float  b_s[32];
  __shared__ float  c_s[8];
  __shared__ unsigned cnt[2];
  if (tid < 32) b_s[tid] = bsum[(tid >> 3) * EMB + jbase + (tid & 7)];
  if (tid < 8)  c_s[tid] = 0.0f;
  if (tid < 2)  cnt[tid] = 0u;
  __syncthreads();   // the ONLY workgroup barrier in this kernel

  const int slotW = lane ^ ((lane >> 3) & 7);   // write-side granule swizzle (per-wave)

  // x(0) prefetch into register
  float xr = (tid < INP) ? x[tid] : 0.0f;

  for (int t = 0; t < SEQ; ++t) {
    const unsigned tt = (unsigned)t;
    const int par = t & 1;

    // ---- 1) issue tagged h-loads FIRST from this WG's mirror (set A) ----
    const u64t* hp = hbuf + ((size_t)par * NMIR + mir) * 2048 + wv * 256 + lane * 4;
    u64t p0 = ALD(hp + 0), p1 = ALD(hp + 1), p2 = ALD(hp + 2), p3 = ALD(hp + 3);

    // ---- 2) stage x from prefetch register; 3) issue x(t+1) prefetch ----
    xs[wv][lane] = xr;
    {
      const int tn = (t + 1 < SEQ) ? t + 1 : t;
      xr = (tid < INP) ? x[(size_t)tn * INP + tid] : 0.0f;
    }

    // ---- 4) x-MAC (hides under h-load latency; same accumulation order) ----
    float4 a0 = make_float4(0, 0, 0, 0), a1 = a0, a2 = a0, a3 = a0;
#pragma unroll
    for (int q = 0; q < 2; ++q) {
      const float4 xv = *(const float4*)&xs[wv][kcL * 8 + q * 4];
      a0.x += wi[0][q * 4 + 0] * xv.x; a0.y += wi[0][q * 4 + 1] * xv.y; a0.z += wi[0][q * 4 + 2] * xv.z; a0.w += wi[0][q * 4 + 3] * xv.w;
      a1.x += wi[1][q * 4 + 0] * xv.x; a1.y += wi[1][q * 4 + 1] * xv.y; a1.z += wi[1][q * 4 + 2] * xv.z; a1.w += wi[1][q * 4 + 3] * xv.w;
      a2.x += wi[2][q * 4 + 0] * xv.x; a2.y += wi[2][q * 4 + 1] * xv.y; a2.z += wi[2][q * 4 + 2] * xv.z; a2.w += wi[2][q * 4 + 3] * xv.w;
      a3.x += wi[3][q * 4 + 0] * xv.x; a3.y += wi[3][q * 4 + 1] * xv.y; a3.z += wi[3][q * 4 + 2] * xv.z; a3.w += wi[3][q * 4 + 3] * xv.w;
    }

    // ---- 5) tag check; 3-deep pipelined retry (wake granularity ~latency/3) ----
    if (hiT(p0) < tt || hiT(p1) < tt || hiT(p2) < tt || hiT(p3) < tt) {
      u64t b0 = ALD(hp + 0), b1 = ALD(hp + 1), b2 = ALD(hp + 2), b3 = ALD(hp + 3);
      u64t c0 = ALD(hp + 0), c1 = ALD(hp + 1), c2 = ALD(hp + 2), c3 = ALD(hp + 3);
      for (;;) {
        // reissue A slot (keeps 3 sets in flight)
        p0 = ALD(hp + 0); p1 = ALD(hp + 1); p2 = ALD(hp + 2); p3 = ALD(hp + 3);
        if (hiT(b0) >= tt && hiT(b1) >= tt && hiT(b2) >= tt && hiT(b3) >= tt) {
          p0 = b0; p1 = b1; p2 = b2; p3 = b3; break;
        }
        b0 = ALD(hp + 0); b1 = ALD(hp + 1); b2 = ALD(hp + 2); b3 = ALD(hp + 3);
        if (hiT(c0) >= tt && hiT(c1) >= tt && hiT(c2) >= tt && hiT(c3) >= tt) {
          p0 = c0; p1 = c1; p2 = c2; p3 = c3; break;
        }
        c0 = ALD(hp + 0); c1 = ALD(hp + 1); c2 = ALD(hp + 2); c3 = ALD(hp + 3);
        if (hiT(p0) >= tt && hiT(p1) >= tt && hiT(p2) >= tt && hiT(p3) >= tt) break;
      }
    }
    hl4[wv][slotW] = make_float4(loF(p0), loF(p1), loF(p2), loF(p3));

    // ---- h-MAC: 4 gates x 32 h (same accumulation order) ----
#pragma unroll
    for (int q = 0; q < 8; ++q) {
      const float4 hv = hl4[wv][kcL * 8 + (q ^ kcL)];   // logical local granule kcL*8+q
      const int b = q * 4;
      a0.x += wh[0][b + 0] * hv.x; a0.y += wh[0][b + 1] * hv.y; a0.z += wh[0][b + 2] * hv.z; a0.w += wh[0][b + 3] * hv.w;
      a1.x += wh[1][b + 0] * hv.x; a1.y += wh[1][b + 1] * hv.y; a1.z += wh[1][b + 2] * hv.z; a1.w += wh[1][b + 3] * hv.w;
      a2.x += wh[2][b + 0] * hv.x; a2.y += wh[2][b + 1] * hv.y; a2.z += wh[2][b + 2] * hv.z; a2.w += wh[2][b + 3] * hv.w;
      a3.x += wh[3][b + 0] * hv.x; a3.y += wh[3][b + 1] * hv.y; a3.z += wh[3][b + 2] * hv.z; a3.w += wh[3][b + 3] * hv.w;
    }

    float r0 = (a0.x + a0.y) + (a0.z + a0.w);
    float r1 = (a1.x + a1.y) + (a1.z + a1.w);
    float r2 = (a2.x + a2.y) + (a2.z + a2.w);
    float r3 = (a3.x + a3.y) + (a3.z + a3.w);
#pragma unroll
    for (int m = 8; m < 64; m <<= 1) {
      r0 += __shfl_xor(r0, m); r1 += __shfl_xor(r1, m);
      r2 += __shfl_xor(r2, m); r3 += __shfl_xor(r3, m);
    }
    if (lane < 8) *(float4*)&partbuf[par][wv][lane][0] = make_float4(r0, r1, r2, r3);

    // ---- last-arriving wave: activation + single-instruction 64-lane mirrored fan-out ----
    unsigned rt = 0u;
    if (lane == 0)
      rt = __hip_atomic_fetch_add(&cnt[par], 1u, __ATOMIC_ACQ_REL, __HIP_MEMORY_SCOPE_WORKGROUP);
    rt = __shfl(rt, 0);
    if (rt == 7u) {
      __builtin_amdgcn_s_setprio(1);
      if (lane == 0)
        __hip_atomic_store(&cnt[par], 0u, __ATOMIC_RELAXED, __HIP_MEMORY_SCOPE_WORKGROUP);
      float hN = 0.0f;
      if (lane < 8) {
        float s0 = 0.f, s1 = 0.f, s2 = 0.f, s3 = 0.f;
#pragma unroll
        for (int w = 0; w < 8; ++w) {   // fixed order: bit-exact vs r6
          const float4 pv = *(const float4*)&partbuf[par][w][lane][0];
          s0 += pv.x; s1 += pv.y; s2 += pv.z; s3 += pv.w;
        }
        const float gi = s0 + b_s[lane], gf = s1 + b_s[8 + lane];
        const float gg = s2 + b_s[16 + lane], go = s3 + b_s[24 + lane];
        const float cN = sigf(gf) * c_s[lane] + sigf(gi) * tanhf(gg);
        c_s[lane] = cN;
        hN = sigf(go) * tanhf(cN);
      }
      asm volatile("s_waitcnt lgkmcnt(0)" ::: "memory");  // cnt reset + c_s retired
      if (t + 1 == SEQ) {
        if (lane < 8) hencbuf[jbase + lane] = hN;   // plain; flushed at kernel end
      } else {
        const float hNb = __shfl(hN, lane & 7);     // lane -> (mirror lane>>3, j lane&7)
        u64t* hb = hbuf + (size_t)(1 - par) * (NMIR * 2048)
                        + (size_t)(lane >> 3) * 2048 + jbase + (lane & 7);
        AST(hb, packFT(hNb, tt + 1));               // one store instr, 8 mirror lines
      }
      __builtin_amdgcn_s_setprio(0);
    }
  }
}

// ---------------- persistent decoder: single copy + 3-deep pipelined tag-poll ----------------
// 16 WGs x 512 thr. WG w owns c-indices [32w,32w+32). Thread: j=tid&31, kc=tid>>5.
// Wave wv consumes hraw floats [60wv..60wv+60) as tagged u64 (single copy; 16 readers/line
// needs no mirrors - r6 showed mirror stores cost more than they save here).
__global__ __launch_bounds__(512) __attribute__((amdgpu_waves_per_eu(2, 2))) void dec_kernel(
    const float* __restrict__ dWih, const float* __restrict__ Wfold,
    const float* __restrict__ btot, const float* __restrict__ henc,
    u64t* __restrict__ hraw, float* __restrict__ out) {
  const int tid  = threadIdx.x;
  const int wg   = blockIdx.x;
  const int j    = tid & 31;
  const int kc   = tid >> 5;   // 0..15
  const int wv   = tid >> 6;   // 0..7
  const int lane = tid & 63;
  const int kcL  = kc & 1;
  const int idx = wg * 32 + j;
  const bool valid = (idx < INP);
  const int id0 = valid ? idx : 0;

  float wd[4][30];
#pragma unroll
  for (int g = 0; g < 4; ++g) {
    const float* wp = Wfold + (size_t)(g * INP + id0) * 480 + kc * 30;
#pragma unroll
    for (int q = 0; q < 15; ++q) {
      const float2 v = valid ? *(const float2*)(wp + 2 * q) : make_float2(0.0f, 0.0f);
      wd[g][q * 2 + 0] = v.x; wd[g][q * 2 + 1] = v.y;
    }
  }
#pragma unroll
  for (int g = 0; g < 4; ++g)
#pragma unroll
    for (int q = 0; q < 30; ++q) PIN(wd[g][q]);

  __shared__ float dl[8][60];              // per-wave staged hraw slice
  __shared__ float partbuf[2][8][32][4];   // parity x wave x j x gate
  __shared__ float b_s[128];
  __shared__ float c_s[32];
  __shared__ unsigned cnt[2];
  if (tid < 128) {
    const int ix = wg * 32 + (tid & 31);
    b_s[tid] = (ix < INP) ? btot[(tid >> 5) * INP + ix] : 0.0f;
  }
  if (tid < 32) c_s[tid] = 0.0f;
  if (tid < 2)  cnt[tid] = 0u;
  __syncthreads();   // only barrier

  for (int t = 0; t < SEQ; ++t) {
    const unsigned tt = (unsigned)t;
    const int par = t & 1;

    if (t > 0) {
      // tagged stage with 3-deep pipelined poll: wave wv needs floats [60wv..60wv+60)
      if (lane < 60) {
        const int fidx = wv * 60 + lane;
        float v = 0.0f;
        if (fidx < INP) {
          const u64t* hp = hraw + (size_t)par * 512 + fidx;
          u64t p = ALD(hp);
          if (hiT(p) < tt) {
            u64t b = ALD(hp);
            u64t c = ALD(hp);
            for (;;) {
              p = ALD(hp);
              if (hiT(b) >= tt) { p = b; break; }
              b = ALD(hp);
              if (hiT(c) >= tt) { p = c; break; }
              c = ALD(hp);
              if (hiT(p) >= tt) break;
            }
          }
          v = loF(p);
        }
        dl[wv][lane] = v;
      }
    }

    float2 acc0 = make_float2(0, 0), acc1 = acc0, acc2 = acc0, acc3 = acc0;
    if (t == 0) {
      if (valid) {
#pragma unroll 4
        for (int q = 0; q < 32; ++q) {
          const float4 hv = *(const float4*)(henc + kc * 128 + 4 * q);
          const float4 w0 = *(const float4*)(dWih + (size_t)(0 * INP + idx) * EMB + kc * 128 + 4 * q);
          const float4 w1 = *(const float4*)(dWih + (size_t)(1 * INP + idx) * EMB + kc * 128 + 4 * q);
          const float4 w2 = *(const float4*)(dWih + (size_t)(2 * INP + idx) * EMB + kc * 128 + 4 * q);
          const float4 w3 = *(const float4*)(dWih + (size_t)(3 * INP + idx) * EMB + kc * 128 + 4 * q);
          acc0.x += w0.x * hv.x + w0.z * hv.z; acc0.y += w0.y * hv.y + w0.w * hv.w;
          acc1.x += w1.x * hv.x + w1.z * hv.z; acc1.y += w1.y * hv.y + w1.w * hv.w;
          acc2.x += w2.x * hv.x + w2.z * hv.z; acc2.y += w2.y * hv.y + w2.w * hv.w;
          acc3.x += w3.x * hv.x + w3.z * hv.z; acc3.y += w3.y * hv.y + w3.w * hv.w;
        }
      }
    } else {
#pragma unroll
      for (int q = 0; q < 15; ++q) {
        const float2 hv = *(const float2*)&dl[wv][kcL * 30 + 2 * q];
        acc0.x += wd[0][q * 2] * hv.x; acc0.y += wd[0][q * 2 + 1] * hv.y;
        acc1.x += wd[1][q * 2] * hv.x; acc1.y += wd[1][q * 2 + 1] * hv.y;
        acc2.x += wd[2][q * 2] * hv.x; acc2.y += wd[2][q * 2 + 1] * hv.y;
        acc3.x += wd[3][q * 2] * hv.x; acc3.y += wd[3][q * 2 + 1] * hv.y;
      }
    }
    float r0 = acc0.x + acc0.y, r1 = acc1.x + acc1.y, r2 = acc2.x + acc2.y, r3 = acc3.x + acc3.y;
    r0 += __shfl_xor(r0, 32); r1 += __shfl_xor(r1, 32);
    r2 += __shfl_xor(r2, 32); r3 += __shfl_xor(r3, 32);
    if (lane < 32) *(float4*)&partbuf[par][wv][lane][0] = make_float4(r0, r1, r2, r3);

    unsigned rt = 0u;
    if (lane == 0)
      rt = __hip_atomic_fetch_add(&cnt[par], 1u, __ATOMIC_ACQ_REL, __HIP_MEMORY_SCOPE_WORKGROUP);
    rt = __shfl(rt, 0);
    if (rt == 7u) {
      __builtin_amdgcn_s_setprio(1);
      if (lane == 0)
        __hip_atomic_store(&cnt[par], 0u, __ATOMIC_RELAXED, __HIP_MEMORY_SCOPE_WORKGROUP);
      if (lane < 32) {
        float s0 = 0.f, s1 = 0.f, s2 = 0.f, s3 = 0.f;
#pragma unroll
        for (int w = 0; w < 8; ++w) {
          const float4 pv = *(const float4*)&partbuf[par][w][lane][0];
          s0 += pv.x; s1 += pv.y; s2 += pv.z; s3 += pv.w;
        }
        const float gi = s0 + b_s[lane], gf = s1 + b_s[32 + lane];
        const float gg = s2 + b_s[64 + lane], go = s3 + b_s[96 + lane];
        const float cN = sigf(gf) * c_s[lane] + sigf(gi) * tanhf(gg);
        c_s[lane] = cN;
        asm volatile("s_waitcnt lgkmcnt(0)" ::: "memory");
        const int ix = wg * 32 + lane;
        if (ix < INP) {
          out[(size_t)(SEQ - 1 - t) * INP + ix] = cN;
          if (t + 1 < SEQ) {
            const float hrN = sigf(go) * tanhf(cN);
            AST(hraw + (size_t)(1 - par) * 512 + ix, packFT(hrN, tt + 1));
          }
        }
      }
      __builtin_amdgcn_s_setprio(0);
    }
  }
}

// ---------------- row softmax in-place on d_out (4096 x 457) ----------------
__global__ __launch_bounds__(512) void softmax_kernel(float* __restrict__ out) {
  const int row = blockIdx.x;
  const int tid = threadIdx.x;
  __shared__ float red[512];
  float* rp = out + (size_t)row * INP;
  float v = (tid < INP) ? rp[tid] : -INFINITY;
  red[tid] = v;
  __syncthreads();
#pragma unroll
  for (int off = 256; off > 0; off >>= 1) {
    if (tid < off) red[tid] = fmaxf(red[tid], red[tid + off]);
    __syncthreads();
  }
  const float m = red[0];
  __syncthreads();
  const float e = (tid < INP) ? expf(v - m) : 0.0f;
  red[tid] = e;
  __syncthreads();
#pragma unroll
  for (int off = 256; off > 0; off >>= 1) {
    if (tid < off) red[tid] = red[tid] + red[tid + off];
    __syncthreads();
  }
  const float s = red[0];
  if (tid < INP) rp[tid] = e / s;
}

extern "C" void kernel_launch(void* const* d_in, const int* in_sizes, int n_in,
                              void* d_out, int out_size, void* d_ws, size_t ws_size,
                              hipStream_t stream) {
  const float* x    = (const float*)d_in[0];
  const float* eWih = (const float*)d_in[1];
  const float* eWhh = (const float*)d_in[2];
  const float* ebih = (const float*)d_in[3];
  const float* ebhh = (const float*)d_in[4];
  const float* dWih = (const float*)d_in[5];
  const float* dWhh = (const float*)d_in[6];
  const float* dbih = (const float*)d_in[7];
  const float* dbhh = (const float*)d_in[8];
  const float* dWhr = (const float*)d_in[9];
  float* out = (float*)d_out;
  char* ws = (char*)d_ws;

  // ws layout:
  // [4096,266240):     hbuf u64[2][NMIR][2048] (tagged h, 8 mirrors; zero => val 0, tag 0)
  // [266240,274432):   hraw u64[2][512]   (tagged decoder h_raw, single copy)
  // [274432,282624):   hencbuf f32[2048]  (plain final encoder h for dec t==0)
  // [282624,315392):   bsum f32[8192]
  // [315392,323584):   btot
  // [327680,+3.51MB):  Wfold 1828x480
  u64t* hbuf   = (u64t*)(ws + 4096);
  u64t* hraw   = (u64t*)(ws + 266240);
  float* hencb = (float*)(ws + 274432);
  float* bsum  = (float*)(ws + 282624);
  float* btot  = (float*)(ws + 315392);
  float* Wfold = (float*)(ws + 327680);

  hipMemsetAsync(ws, 0, 274432, stream);  // hbuf (all mirrors) + hraw (tags=0, vals=0)
  bias_kernel<<<40, 256, 0, stream>>>(ebih, ebhh, dbih, dbhh, bsum, btot);
  fold_gemm<<<dim3(8, 29), 256, 0, stream>>>(dWih, dWhh, dWhr, Wfold);
  enc_kernel<<<NWG_E, 512, 0, stream>>>(x, eWih, eWhh, bsum, hbuf, hencb);
  dec_kernel<<<NWG_D, 512, 0, stream>>>(dWih, Wfold, btot, hencb, hraw, out);
  softmax_kernel<<<SEQ, 512, 0, stream>>>(out);
}

// Round 8
// 22598.450 us; speedup vs baseline: 1.2530x; 1.2530x over previous
//
#include <hip/hip_runtime.h>
#include <cmath>

#define SEQ 4096
#define INP 457
#define EMB 2048
#define NWG_E 256   // encoder: 1 WG (512 thr) per CU; weights pinned in VGPRs
#define NWG_D 16    // decoder: 16 WGs x 32 c-indices = 512 >= 457
#define NMIR 8      // enc broadcast mirrors (readers/line 256 -> 32)

typedef unsigned long long u64t;

__device__ __forceinline__ float sigf(float v) { return 1.0f / (1.0f + expf(-v)); }

// Opaque pin: value becomes output of an opaque asm -> compiler cannot rematerialize
#define PIN(v) asm volatile("" : "+v"(v))

#define ALD(p)    __hip_atomic_load((p), __ATOMIC_RELAXED, __HIP_MEMORY_SCOPE_AGENT)
#define AST(p, v) __hip_atomic_store((p), (v), __ATOMIC_RELAXED, __HIP_MEMORY_SCOPE_AGENT)

__device__ __forceinline__ float    loF(u64t p) { return __builtin_bit_cast(float, (unsigned)p); }
__device__ __forceinline__ unsigned hiT(u64t p) { return (unsigned)(p >> 32); }
__device__ __forceinline__ u64t packFT(float v, unsigned tag) {
  return ((u64t)tag << 32) | (u64t)__builtin_bit_cast(unsigned, v);
}

// ---------------- bias precompute ----------------
__global__ void bias_kernel(const float* __restrict__ ebih, const float* __restrict__ ebhh,
                            const float* __restrict__ dbih, const float* __restrict__ dbhh,
                            float* __restrict__ bsum, float* __restrict__ btot) {
  int i = blockIdx.x * 256 + threadIdx.x;
  if (i < 4 * EMB) bsum[i] = ebih[i] + ebhh[i];
  if (i < 4 * INP) btot[i] = dbih[i] + dbhh[i];
}

// ---------------- Wfold = (dec_Wih + dec_Whh) @ dec_Whr  (1828 x 480, pad cols zero) ----------------
__global__ __launch_bounds__(256) void fold_gemm(const float* __restrict__ dWih,
                                                 const float* __restrict__ dWhh,
                                                 const float* __restrict__ dWhr,
                                                 float* __restrict__ C) {
  const int bx = blockIdx.x, by = blockIdx.y;
  const int tid = threadIdx.x;
  const int tx = tid & 15, ty = tid >> 4;
  __shared__ float As[16][65];
  __shared__ float Bs[16][65];
  float acc[4][4] = {};
  for (int k0 = 0; k0 < EMB; k0 += 16) {
#pragma unroll
    for (int e = 0; e < 4; ++e) {
      int eid = tid * 4 + e;
      int m = eid >> 4, k = eid & 15;
      int row = by * 64 + m;
      float v = 0.0f;
      if (row < 4 * INP) {
        size_t a = (size_t)row * EMB + k0 + k;
        v = dWih[a] + dWhh[a];
      }
      As[k][m] = v;
    }
#pragma unroll
    for (int e = 0; e < 4; ++e) {
      int eid = tid * 4 + e;
      int k = eid >> 6, c = eid & 63;
      int col = bx * 64 + c;
      Bs[k][c] = (col < INP) ? dWhr[(size_t)(k0 + k) * INP + col] : 0.0f;
    }
    __syncthreads();
#pragma unroll
    for (int k = 0; k < 16; ++k) {
      float a0 = As[k][ty * 4 + 0], a1 = As[k][ty * 4 + 1], a2 = As[k][ty * 4 + 2], a3 = As[k][ty * 4 + 3];
      float b0 = Bs[k][tx * 4 + 0], b1 = Bs[k][tx * 4 + 1], b2 = Bs[k][tx * 4 + 2], b3 = Bs[k][tx * 4 + 3];
      acc[0][0] += a0 * b0; acc[0][1] += a0 * b1; acc[0][2] += a0 * b2; acc[0][3] += a0 * b3;
      acc[1][0] += a1 * b0; acc[1][1] += a1 * b1; acc[1][2] += a1 * b2; acc[1][3] += a1 * b3;
      acc[2][0] += a2 * b0; acc[2][1] += a2 * b1; acc[2][2] += a2 * b2; acc[2][3] += a2 * b3;
      acc[3][0] += a3 * b0; acc[3][1] += a3 * b1; acc[3][2] += a3 * b2; acc[3][3] += a3 * b3;
    }
    __syncthreads();
  }
#pragma unroll
  for (int i = 0; i < 4; ++i) {
    int row = by * 64 + ty * 4 + i;
    if (row >= 4 * INP) continue;
#pragma unroll
    for (int j = 0; j < 4; ++j) {
      int col = bx * 64 + tx * 4 + j;
      if (col < 480) C[(size_t)row * 480 + col] = acc[i][j];
    }
  }
}

// ---------------- persistent encoder (r6 form: mirrors + simple sleep-throttled poll) ----------------
// 256 WGs x 512 thr. WG w owns h[8w..8w+8). Thread: j=tid&7, kc=tid>>3, wave wv=tid>>6.
// Wave wv consumes h[256wv..256wv+256) as tagged u64 (float val | u32 step-tag), from
// MIRROR (wg & 7); producers fan out to all 8 mirrors with ONE 64-lane store.
// Race-freedom: tag travels with value in one u64; every WG posts tag t+1 to ALL mirrors
// after all 8 waves' MAC(t) (fetch_add gate), so a producer overwrites slot t with tag t+2
// only after observing ALL 256 WGs' t+1 tags -> no reader can see a future tag.
__global__ __launch_bounds__(512) __attribute__((amdgpu_waves_per_eu(2, 2))) void enc_kernel(
    const float* __restrict__ x, const float* __restrict__ Wih,
    const float* __restrict__ Whh, const float* __restrict__ bsum,
    u64t* __restrict__ hbuf, float* __restrict__ hencbuf) {
  const int tid  = threadIdx.x;
  const int wg   = blockIdx.x;
  const int j    = tid & 7;
  const int kc   = tid >> 3;   // 0..63 global k-chunk
  const int wv   = tid >> 6;   // 0..7
  const int lane = tid & 63;
  const int kcL  = kc & 7;     // k-chunk within wave
  const int jbase = wg * 8;
  const int mir  = wg & (NMIR - 1);

  float wh[4][32];
  float wi[4][8];
#pragma unroll
  for (int g = 0; g < 4; ++g) {
    const size_t row = (size_t)(g * EMB + jbase + j);
    const float* wp = Whh + row * EMB + kc * 32;
#pragma unroll
    for (int q = 0; q < 8; ++q) {
      const float4 v = *(const float4*)(wp + 4 * q);
      wh[g][q * 4 + 0] = v.x; wh[g][q * 4 + 1] = v.y;
      wh[g][q * 4 + 2] = v.z; wh[g][q * 4 + 3] = v.w;
    }
    const float* ip = Wih + row * INP;
#pragma unroll
    for (int i = 0; i < 8; ++i) {
      const int c = kc * 8 + i;
      wi[g][i] = (c < INP) ? ip[c] : 0.0f;
    }
  }
#pragma unroll
  for (int g = 0; g < 4; ++g) {
#pragma unroll
    for (int q = 0; q < 32; ++q) PIN(wh[g][q]);
#pragma unroll
    for (int q = 0; q < 8; ++q) PIN(wi[g][q]);
  }

  __shared__ float4 hl4[8][64];          // per-wave h granules (XOR-swizzled within wave)
  __shared__ float  xs[8][64];           // per-wave x slice
  __shared__ float  partbuf[2][8][8][4]; // parity x wave x j x gate
  __shared__ float  b_s[32];
  __shared__ float  c_s[8];
  __shared__ unsigned cnt[2];
  if (tid < 32) b_s[tid] = bsum[(tid >> 3) * EMB + jbase + (tid & 7)];
  if (tid < 8)  c_s[tid] = 0.0f;
  if (tid < 2)  cnt[tid] = 0u;
  __syncthreads();   // the ONLY workgroup barrier in this kernel

  const int slotW = lane ^ ((lane >> 3) & 7);   // write-side granule swizzle (per-wave)

  // x(0) prefetch into register
  float xr = (tid < INP) ? x[tid] : 0.0f;

  for (int t = 0; t < SEQ; ++t) {
    const unsigned tt = (unsigned)t;
    const int par = t & 1;

    // ---- 1) issue tagged h-loads FIRST from this WG's mirror ----
    const u64t* hp = hbuf + ((size_t)par * NMIR + mir) * 2048 + wv * 256 + lane * 4;
    u64t p0 = ALD(hp + 0), p1 = ALD(hp + 1), p2 = ALD(hp + 2), p3 = ALD(hp + 3);

    // ---- 2) stage x from prefetch register; 3) issue x(t+1) prefetch ----
    xs[wv][lane] = xr;
    {
      const int tn = (t + 1 < SEQ) ? t + 1 : t;
      xr = (tid < INP) ? x[(size_t)tn * INP + tid] : 0.0f;
    }

    // ---- 4) x-MAC (hides under h-load latency; same accumulation order) ----
    float4 a0 = make_float4(0, 0, 0, 0), a1 = a0, a2 = a0, a3 = a0;
#pragma unroll
    for (int q = 0; q < 2; ++q) {
      const float4 xv = *(const float4*)&xs[wv][kcL * 8 + q * 4];
      a0.x += wi[0][q * 4 + 0] * xv.x; a0.y += wi[0][q * 4 + 1] * xv.y; a0.z += wi[0][q * 4 + 2] * xv.z; a0.w += wi[0][q * 4 + 3] * xv.w;
      a1.x += wi[1][q * 4 + 0] * xv.x; a1.y += wi[1][q * 4 + 1] * xv.y; a1.z += wi[1][q * 4 + 2] * xv.z; a1.w += wi[1][q * 4 + 3] * xv.w;
      a2.x += wi[2][q * 4 + 0] * xv.x; a2.y += wi[2][q * 4 + 1] * xv.y; a2.z += wi[2][q * 4 + 2] * xv.z; a2.w += wi[2][q * 4 + 3] * xv.w;
      a3.x += wi[3][q * 4 + 0] * xv.x; a3.y += wi[3][q * 4 + 1] * xv.y; a3.z += wi[3][q * 4 + 2] * xv.z; a3.w += wi[3][q * 4 + 3] * xv.w;
    }

    // ---- 5) tag check + sleep-throttled retry; LDS transpose stage ----
    while (hiT(p0) < tt || hiT(p1) < tt || hiT(p2) < tt || hiT(p3) < tt) {
      __builtin_amdgcn_s_sleep(1);
      p0 = ALD(hp + 0); p1 = ALD(hp + 1); p2 = ALD(hp + 2); p3 = ALD(hp + 3);
    }
    hl4[wv][slotW] = make_float4(loF(p0), loF(p1), loF(p2), loF(p3));

    // ---- h-MAC: 4 gates x 32 h (same accumulation order) ----
#pragma unroll
    for (int q = 0; q < 8; ++q) {
      const float4 hv = hl4[wv][kcL * 8 + (q ^ kcL)];   // logical local granule kcL*8+q
      const int b = q * 4;
      a0.x += wh[0][b + 0] * hv.x; a0.y += wh[0][b + 1] * hv.y; a0.z += wh[0][b + 2] * hv.z; a0.w += wh[0][b + 3] * hv.w;
      a1.x += wh[1][b + 0] * hv.x; a1.y += wh[1][b + 1] * hv.y; a1.z += wh[1][b + 2] * hv.z; a1.w += wh[1][b + 3] * hv.w;
      a2.x += wh[2][b + 0] * hv.x; a2.y += wh[2][b + 1] * hv.y; a2.z += wh[2][b + 2] * hv.z; a2.w += wh[2][b + 3] * hv.w;
      a3.x += wh[3][b + 0] * hv.x; a3.y += wh[3][b + 1] * hv.y; a3.z += wh[3][b + 2] * hv.z; a3.w += wh[3][b + 3] * hv.w;
    }

    float r0 = (a0.x + a0.y) + (a0.z + a0.w);
    float r1 = (a1.x + a1.y) + (a1.z + a1.w);
    float r2 = (a2.x + a2.y) + (a2.z + a2.w);
    float r3 = (a3.x + a3.y) + (a3.z + a3.w);
#pragma unroll
    for (int m = 8; m < 64; m <<= 1) {
      r0 += __shfl_xor(r0, m); r1 += __shfl_xor(r1, m);
      r2 += __shfl_xor(r2, m); r3 += __shfl_xor(r3, m);
    }
    if (lane < 8) *(float4*)&partbuf[par][wv][lane][0] = make_float4(r0, r1, r2, r3);

    // ---- last-arriving wave: activation + single-instruction 64-lane mirrored fan-out ----
    unsigned rt = 0u;
    if (lane == 0)
      rt = __hip_atomic_fetch_add(&cnt[par], 1u, __ATOMIC_ACQ_REL, __HIP_MEMORY_SCOPE_WORKGROUP);
    rt = __shfl(rt, 0);
    if (rt == 7u) {
      __builtin_amdgcn_s_setprio(1);
      if (lane == 0)
        __hip_atomic_store(&cnt[par], 0u, __ATOMIC_RELAXED, __HIP_MEMORY_SCOPE_WORKGROUP);
      float hN = 0.0f;
      if (lane < 8) {
        float s0 = 0.f, s1 = 0.f, s2 = 0.f, s3 = 0.f;
#pragma unroll
        for (int w = 0; w < 8; ++w) {   // fixed order: bit-exact vs r6
          const float4 pv = *(const float4*)&partbuf[par][w][lane][0];
          s0 += pv.x; s1 += pv.y; s2 += pv.z; s3 += pv.w;
        }
        const float gi = s0 + b_s[lane], gf = s1 + b_s[8 + lane];
        const float gg = s2 + b_s[16 + lane], go = s3 + b_s[24 + lane];
        const float cN = sigf(gf) * c_s[lane] + sigf(gi) * tanhf(gg);
        c_s[lane] = cN;
        hN = sigf(go) * tanhf(cN);
      }
      asm volatile("s_waitcnt lgkmcnt(0)" ::: "memory");  // cnt reset + c_s retired
      if (t + 1 == SEQ) {
        if (lane < 8) hencbuf[jbase + lane] = hN;   // plain; flushed at kernel end
      } else {
        const float hNb = __shfl(hN, lane & 7);     // lane -> (mirror lane>>3, j lane&7)
        u64t* hb = hbuf + (size_t)(1 - par) * (NMIR * 2048)
                        + (size_t)(lane >> 3) * 2048 + jbase + (lane & 7);
        AST(hb, packFT(hNb, tt + 1));               // one store instr, 8 mirror lines
      }
      __builtin_amdgcn_s_setprio(0);
    }
  }
}

// ---------------- persistent decoder (r4 form: single copy, simple poll, single store) ----------------
// 16 WGs x 512 thr. WG w owns c-indices [32w,32w+32). Thread: j=tid&31, kc=tid>>5.
// Wave wv consumes hraw floats [60wv..60wv+60) as tagged u64.
__global__ __launch_bounds__(512) __attribute__((amdgpu_waves_per_eu(2, 2))) void dec_kernel(
    const float* __restrict__ dWih, const float* __restrict__ Wfold,
    const float* __restrict__ btot, const float* __restrict__ henc,
    u64t* __restrict__ hraw, float* __restrict__ out) {
  const int tid  = threadIdx.x;
  const int wg   = blockIdx.x;
  const int j    = tid & 31;
  const int kc   = tid >> 5;   // 0..15
  const int wv   = tid >> 6;   // 0..7
  const int lane = tid & 63;
  const int kcL  = kc & 1;
  const int idx = wg * 32 + j;
  const bool valid = (idx < INP);
  const int id0 = valid ? idx : 0;

  float wd[4][30];
#pragma unroll
  for (int g = 0; g < 4; ++g) {
    const float* wp = Wfold + (size_t)(g * INP + id0) * 480 + kc * 30;
#pragma unroll
    for (int q = 0; q < 15; ++q) {
      const float2 v = valid ? *(const float2*)(wp + 2 * q) : make_float2(0.0f, 0.0f);
      wd[g][q * 2 + 0] = v.x; wd[g][q * 2 + 1] = v.y;
    }
  }
#pragma unroll
  for (int g = 0; g < 4; ++g)
#pragma unroll
    for (int q = 0; q < 30; ++q) PIN(wd[g][q]);

  __shared__ float dl[8][60];              // per-wave staged hraw slice
  __shared__ float partbuf[2][8][32][4];   // parity x wave x j x gate
  __shared__ float b_s[128];
  __shared__ float c_s[32];
  __shared__ unsigned cnt[2];
  if (tid < 128) {
    const int ix = wg * 32 + (tid & 31);
    b_s[tid] = (ix < INP) ? btot[(tid >> 5) * INP + ix] : 0.0f;
  }
  if (tid < 32) c_s[tid] = 0.0f;
  if (tid < 2)  cnt[tid] = 0u;
  __syncthreads();   // only barrier

  for (int t = 0; t < SEQ; ++t) {
    const unsigned tt = (unsigned)t;
    const int par = t & 1;

    if (t > 0) {
      // direct tagged stage: wave wv needs floats [60wv..60wv+60)
      if (lane < 60) {
        const int fidx = wv * 60 + lane;
        float v = 0.0f;
        if (fidx < INP) {
          const u64t* hp = hraw + (size_t)par * 512 + fidx;
          u64t p = ALD(hp);
          while (hiT(p) < tt) p = ALD(hp);
          v = loF(p);
        }
        dl[wv][lane] = v;
      }
    }

    float2 acc0 = make_float2(0, 0), acc1 = acc0, acc2 = acc0, acc3 = acc0;
    if (t == 0) {
      if (valid) {
#pragma unroll 4
        for (int q = 0; q < 32; ++q) {
          const float4 hv = *(const float4*)(henc + kc * 128 + 4 * q);
          const float4 w0 = *(const float4*)(dWih + (size_t)(0 * INP + idx) * EMB + kc * 128 + 4 * q);
          const float4 w1 = *(const float4*)(dWih + (size_t)(1 * INP + idx) * EMB + kc * 128 + 4 * q);
          const float4 w2 = *(const float4*)(dWih + (size_t)(2 * INP + idx) * EMB + kc * 128 + 4 * q);
          const float4 w3 = *(const float4*)(dWih + (size_t)(3 * INP + idx) * EMB + kc * 128 + 4 * q);
          acc0.x += w0.x * hv.x + w0.z * hv.z; acc0.y += w0.y * hv.y + w0.w * hv.w;
          acc1.x += w1.x * hv.x + w1.z * hv.z; acc1.y += w1.y * hv.y + w1.w * hv.w;
          acc2.x += w2.x * hv.x + w2.z * hv.z; acc2.y += w2.y * hv.y + w2.w * hv.w;
          acc3.x += w3.x * hv.x + w3.z * hv.z; acc3.y += w3.y * hv.y + w3.w * hv.w;
        }
      }
    } else {
#pragma unroll
      for (int q = 0; q < 15; ++q) {
        const float2 hv = *(const float2*)&dl[wv][kcL * 30 + 2 * q];
        acc0.x += wd[0][q * 2] * hv.x; acc0.y += wd[0][q * 2 + 1] * hv.y;
        acc1.x += wd[1][q * 2] * hv.x; acc1.y += wd[1][q * 2 + 1] * hv.y;
        acc2.x += wd[2][q * 2] * hv.x; acc2.y += wd[2][q * 2 + 1] * hv.y;
        acc3.x += wd[3][q * 2] * hv.x; acc3.y += wd[3][q * 2 + 1] * hv.y;
      }
    }
    float r0 = acc0.x + acc0.y, r1 = acc1.x + acc1.y, r2 = acc2.x + acc2.y, r3 = acc3.x + acc3.y;
    r0 += __shfl_xor(r0, 32); r1 += __shfl_xor(r1, 32);
    r2 += __shfl_xor(r2, 32); r3 += __shfl_xor(r3, 32);
    if (lane < 32) *(float4*)&partbuf[par][wv][lane][0] = make_float4(r0, r1, r2, r3);

    unsigned rt = 0u;
    if (lane == 0)
      rt = __hip_atomic_fetch_add(&cnt[par], 1u, __ATOMIC_ACQ_REL, __HIP_MEMORY_SCOPE_WORKGROUP);
    rt = __shfl(rt, 0);
    if (rt == 7u) {
      __builtin_amdgcn_s_setprio(1);
      if (lane == 0)
        __hip_atomic_store(&cnt[par], 0u, __ATOMIC_RELAXED, __HIP_MEMORY_SCOPE_WORKGROUP);
      if (lane < 32) {
        float s0 = 0.f, s1 = 0.f, s2 = 0.f, s3 = 0.f;
#pragma unroll
        for (int w = 0; w < 8; ++w) {
          const float4 pv = *(const float4*)&partbuf[par][w][lane][0];
          s0 += pv.x; s1 += pv.y; s2 += pv.z; s3 += pv.w;
        }
        const float gi = s0 + b_s[lane], gf = s1 + b_s[32 + lane];
        const float gg = s2 + b_s[64 + lane], go = s3 + b_s[96 + lane];
        const float cN = sigf(gf) * c_s[lane] + sigf(gi) * tanhf(gg);
        c_s[lane] = cN;
        asm volatile("s_waitcnt lgkmcnt(0)" ::: "memory");
        const int ix = wg * 32 + lane;
        if (ix < INP) {
          out[(size_t)(SEQ - 1 - t) * INP + ix] = cN;
          if (t + 1 < SEQ) {
            const float hrN = sigf(go) * tanhf(cN);
            AST(hraw + (size_t)(1 - par) * 512 + ix, packFT(hrN, tt + 1));
          }
        }
      }
      __builtin_amdgcn_s_setprio(0);
    }
  }
}

// ---------------- row softmax in-place on d_out (4096 x 457) ----------------
__global__ __launch_bounds__(512) void softmax_kernel(float* __restrict__ out) {
  const int row = blockIdx.x;
  const int tid = threadIdx.x;
  __shared__ float red[512];
  float* rp = out + (size_t)row * INP;
  float v = (tid < INP) ? rp[tid] : -INFINITY;
  red[tid] = v;
  __syncthreads();
#pragma unroll
  for (int off = 256; off > 0; off >>= 1) {
    if (tid < off) red[tid] = fmaxf(red[tid], red[tid + off]);
    __syncthreads();
  }
  const float m = red[0];
  __syncthreads();
  const float e = (tid < INP) ? expf(v - m) : 0.0f;
  red[tid] = e;
  __syncthreads();
#pragma unroll
  for (int off = 256; off > 0; off >>= 1) {
    if (tid < off) red[tid] = red[tid] + red[tid + off];
    __syncthreads();
  }
  const float s = red[0];
  if (tid < INP) rp[tid] = e / s;
}

extern "C" void kernel_launch(void* const* d_in, const int* in_sizes, int n_in,
                              void* d_out, int out_size, void* d_ws, size_t ws_size,
                              hipStream_t stream) {
  const float* x    = (const float*)d_in[0];
  const float* eWih = (const float*)d_in[1];
  const float* eWhh = (const float*)d_in[2];
  const float* ebih = (const float*)d_in[3];
  const float* ebhh = (const float*)d_in[4];
  const float* dWih = (const float*)d_in[5];
  const float* dWhh = (const float*)d_in[6];
  const float* dbih = (const float*)d_in[7];
  const float* dbhh = (const float*)d_in[8];
  const float* dWhr = (const float*)d_in[9];
  float* out = (float*)d_out;
  char* ws = (char*)d_ws;

  // ws layout:
  // [4096,266240):     hbuf u64[2][NMIR][2048] (tagged h, 8 mirrors; zero => val 0, tag 0)
  // [266240,274432):   hraw u64[2][512]   (tagged decoder h_raw, single copy)
  // [274432,282624):   hencbuf f32[2048]  (plain final encoder h for dec t==0)
  // [282624,315392):   bsum f32[8192]
  // [315392,323584):   btot
  // [327680,+3.51MB):  Wfold 1828x480
  u64t* hbuf   = (u64t*)(ws + 4096);
  u64t* hraw   = (u64t*)(ws + 266240);
  float* hencb = (float*)(ws + 274432);
  float* bsum  = (float*)(ws + 282624);
  float* btot  = (float*)(ws + 315392);
  float* Wfold = (float*)(ws + 327680);

  hipMemsetAsync(ws, 0, 274432, stream);  // hbuf (all mirrors) + hraw (tags=0, vals=0)
  bias_kernel<<<40, 256, 0, stream>>>(ebih, ebhh, dbih, dbhh, bsum, btot);
  fold_gemm<<<dim3(8, 29), 256, 0, stream>>>(dWih, dWhh, dWhr, Wfold);
  enc_kernel<<<NWG_E, 512, 0, stream>>>(x, eWih, eWhh, bsum, hbuf, hencb);
  dec_kernel<<<NWG_D, 512, 0, stream>>>(dWih, Wfold, btot, hencb, hraw, out);
  softmax_kernel<<<SEQ, 512, 0, stream>>>(out);
}

// Round 9
// 22069.856 us; speedup vs baseline: 1.2830x; 1.0240x over previous
//
#include <hip/hip_runtime.h>
#include <cmath>

#define SEQ 4096
#define INP 457
#define EMB 2048
#define NWG_E 256   // encoder: 1 WG (512 thr) per CU; weights pinned in VGPRs
#define NWG_D 16    // decoder: 16 WGs x 32 c-indices = 512 >= 457
#define NMIR 8      // enc broadcast mirrors (readers/line 256 -> 32)

typedef unsigned long long u64t;

__device__ __forceinline__ float sigf(float v) { return 1.0f / (1.0f + expf(-v)); }

// Opaque pin: value becomes output of an opaque asm -> compiler cannot rematerialize
#define PIN(v) asm volatile("" : "+v"(v))

#define ALD(p)    __hip_atomic_load((p), __ATOMIC_RELAXED, __HIP_MEMORY_SCOPE_AGENT)
#define AST(p, v) __hip_atomic_store((p), (v), __ATOMIC_RELAXED, __HIP_MEMORY_SCOPE_AGENT)

__device__ __forceinline__ float    loF(u64t p) { return __builtin_bit_cast(float, (unsigned)p); }
__device__ __forceinline__ unsigned hiT(u64t p) { return (unsigned)(p >> 32); }
__device__ __forceinline__ u64t packFT(float v, unsigned tag) {
  return ((u64t)tag << 32) | (u64t)__builtin_bit_cast(unsigned, v);
}

// ---------------- bias precompute ----------------
__global__ void bias_kernel(const float* __restrict__ ebih, const float* __restrict__ ebhh,
                            const float* __restrict__ dbih, const float* __restrict__ dbhh,
                            float* __restrict__ bsum, float* __restrict__ btot) {
  int i = blockIdx.x * 256 + threadIdx.x;
  if (i < 4 * EMB) bsum[i] = ebih[i] + ebhh[i];
  if (i < 4 * INP) btot[i] = dbih[i] + dbhh[i];
}

// ---------------- Wfold = (dec_Wih + dec_Whh) @ dec_Whr  (1828 x 480, pad cols zero) ----------------
__global__ __launch_bounds__(256) void fold_gemm(const float* __restrict__ dWih,
                                                 const float* __restrict__ dWhh,
                                                 const float* __restrict__ dWhr,
                                                 float* __restrict__ C) {
  const int bx = blockIdx.x, by = blockIdx.y;
  const int tid = threadIdx.x;
  const int tx = tid & 15, ty = tid >> 4;
  __shared__ float As[16][65];
  __shared__ float Bs[16][65];
  float acc[4][4] = {};
  for (int k0 = 0; k0 < EMB; k0 += 16) {
#pragma unroll
    for (int e = 0; e < 4; ++e) {
      int eid = tid * 4 + e;
      int m = eid >> 4, k = eid & 15;
      int row = by * 64 + m;
      float v = 0.0f;
      if (row < 4 * INP) {
        size_t a = (size_t)row * EMB + k0 + k;
        v = dWih[a] + dWhh[a];
      }
      As[k][m] = v;
    }
#pragma unroll
    for (int e = 0; e < 4; ++e) {
      int eid = tid * 4 + e;
      int k = eid >> 6, c = eid & 63;
      int col = bx * 64 + c;
      Bs[k][c] = (col < INP) ? dWhr[(size_t)(k0 + k) * INP + col] : 0.0f;
    }
    __syncthreads();
#pragma unroll
    for (int k = 0; k < 16; ++k) {
      float a0 = As[k][ty * 4 + 0], a1 = As[k][ty * 4 + 1], a2 = As[k][ty * 4 + 2], a3 = As[k][ty * 4 + 3];
      float b0 = Bs[k][tx * 4 + 0], b1 = Bs[k][tx * 4 + 1], b2 = Bs[k][tx * 4 + 2], b3 = Bs[k][tx * 4 + 3];
      acc[0][0] += a0 * b0; acc[0][1] += a0 * b1; acc[0][2] += a0 * b2; acc[0][3] += a0 * b3;
      acc[1][0] += a1 * b0; acc[1][1] += a1 * b1; acc[1][2] += a1 * b2; acc[1][3] += a1 * b3;
      acc[2][0] += a2 * b0; acc[2][1] += a2 * b1; acc[2][2] += a2 * b2; acc[2][3] += a2 * b3;
      acc[3][0] += a3 * b0; acc[3][1] += a3 * b1; acc[3][2] += a3 * b2; acc[3][3] += a3 * b3;
    }
    __syncthreads();
  }
#pragma unroll
  for (int i = 0; i < 4; ++i) {
    int row = by * 64 + ty * 4 + i;
    if (row >= 4 * INP) continue;
#pragma unroll
    for (int j = 0; j < 4; ++j) {
      int col = bx * 64 + tx * 4 + j;
      if (col < 480) C[(size_t)row * 480 + col] = acc[i][j];
    }
  }
}

// ---------------- persistent encoder (r8 + biases in pinned registers) ----------------
// 256 WGs x 512 thr. WG w owns h[8w..8w+8). Thread: j=tid&7, kc=tid>>3, wave wv=tid>>6.
// Wave wv consumes h[256wv..256wv+256) as tagged u64 (float val | u32 step-tag), from
// MIRROR (wg & 7); producers fan out to all 8 mirrors with ONE 64-lane store.
// Race-freedom: tag travels with value in one u64; every WG posts tag t+1 to ALL mirrors
// after all 8 waves' MAC(t) (fetch_add gate), so a producer overwrites slot t with tag t+2
// only after observing ALL 256 WGs' t+1 tags -> no reader can see a future tag.
__global__ __launch_bounds__(512) __attribute__((amdgpu_waves_per_eu(2, 2))) void enc_kernel(
    const float* __restrict__ x, const float* __restrict__ Wih,
    const float* __restrict__ Whh, const float* __restrict__ bsum,
    u64t* __restrict__ hbuf, float* __restrict__ hencbuf) {
  const int tid  = threadIdx.x;
  const int wg   = blockIdx.x;
  const int j    = tid & 7;
  const int kc   = tid >> 3;   // 0..63 global k-chunk
  const int wv   = tid >> 6;   // 0..7
  const int lane = tid & 63;
  const int kcL  = kc & 7;     // k-chunk within wave
  const int jbase = wg * 8;
  const int mir  = wg & (NMIR - 1);

  float wh[4][32];
  float wi[4][8];
#pragma unroll
  for (int g = 0; g < 4; ++g) {
    const size_t row = (size_t)(g * EMB + jbase + j);
    const float* wp = Whh + row * EMB + kc * 32;
#pragma unroll
    for (int q = 0; q < 8; ++q) {
      const float4 v = *(const float4*)(wp + 4 * q);
      wh[g][q * 4 + 0] = v.x; wh[g][q * 4 + 1] = v.y;
      wh[g][q * 4 + 2] = v.z; wh[g][q * 4 + 3] = v.w;
    }
    const float* ip = Wih + row * INP;
#pragma unroll
    for (int i = 0; i < 8; ++i) {
      const int c = kc * 8 + i;
      wi[g][i] = (c < INP) ? ip[c] : 0.0f;
    }
  }
#pragma unroll
  for (int g = 0; g < 4; ++g) {
#pragma unroll
    for (int q = 0; q < 32; ++q) PIN(wh[g][q]);
#pragma unroll
    for (int q = 0; q < 8; ++q) PIN(wi[g][q]);
  }

  // gate biases in registers (act path uses them; pinned so no remat/global reload)
  const int jb8 = lane & 7;
  float bi0 = bsum[0 * EMB + jbase + jb8];
  float bi1 = bsum[1 * EMB + jbase + jb8];
  float bi2 = bsum[2 * EMB + jbase + jb8];
  float bi3 = bsum[3 * EMB + jbase + jb8];
  PIN(bi0); PIN(bi1); PIN(bi2); PIN(bi3);

  __shared__ float4 hl4[8][64];          // per-wave h granules (XOR-swizzled within wave)
  __shared__ float  xs[8][64];           // per-wave x slice
  __shared__ float  partbuf[2][8][8][4]; // parity x wave x j x gate
  __shared__ float  c_s[8];
  __shared__ unsigned cnt[2];
  if (tid < 8)  c_s[tid] = 0.0f;
  if (tid < 2)  cnt[tid] = 0u;
  __syncthreads();   // the ONLY workgroup barrier in this kernel

  const int slotW = lane ^ ((lane >> 3) & 7);   // write-side granule swizzle (per-wave)

  // x(0) prefetch into register
  float xr = (tid < INP) ? x[tid] : 0.0f;

  for (int t = 0; t < SEQ; ++t) {
    const unsigned tt = (unsigned)t;
    const int par = t & 1;

    // ---- 1) issue tagged h-loads FIRST from this WG's mirror ----
    const u64t* hp = hbuf + ((size_t)par * NMIR + mir) * 2048 + wv * 256 + lane * 4;
    u64t p0 = ALD(hp + 0), p1 = ALD(hp + 1), p2 = ALD(hp + 2), p3 = ALD(hp + 3);

    // ---- 2) stage x from prefetch register; 3) issue x(t+1) prefetch ----
    xs[wv][lane] = xr;
    {
      const int tn = (t + 1 < SEQ) ? t + 1 : t;
      xr = (tid < INP) ? x[(size_t)tn * INP + tid] : 0.0f;
    }

    // ---- 4) x-MAC (hides under h-load latency; same accumulation order) ----
    float4 a0 = make_float4(0, 0, 0, 0), a1 = a0, a2 = a0, a3 = a0;
#pragma unroll
    for (int q = 0; q < 2; ++q) {
      const float4 xv = *(const float4*)&xs[wv][kcL * 8 + q * 4];
      a0.x += wi[0][q * 4 + 0] * xv.x; a0.y += wi[0][q * 4 + 1] * xv.y; a0.z += wi[0][q * 4 + 2] * xv.z; a0.w += wi[0][q * 4 + 3] * xv.w;
      a1.x += wi[1][q * 4 + 0] * xv.x; a1.y += wi[1][q * 4 + 1] * xv.y; a1.z += wi[1][q * 4 + 2] * xv.z; a1.w += wi[1][q * 4 + 3] * xv.w;
      a2.x += wi[2][q * 4 + 0] * xv.x; a2.y += wi[2][q * 4 + 1] * xv.y; a2.z += wi[2][q * 4 + 2] * xv.z; a2.w += wi[2][q * 4 + 3] * xv.w;
      a3.x += wi[3][q * 4 + 0] * xv.x; a3.y += wi[3][q * 4 + 1] * xv.y; a3.z += wi[3][q * 4 + 2] * xv.z; a3.w += wi[3][q * 4 + 3] * xv.w;
    }

    // ---- 5) tag check + sleep-throttled retry; LDS transpose stage ----
    while (hiT(p0) < tt || hiT(p1) < tt || hiT(p2) < tt || hiT(p3) < tt) {
      __builtin_amdgcn_s_sleep(1);
      p0 = ALD(hp + 0); p1 = ALD(hp + 1); p2 = ALD(hp + 2); p3 = ALD(hp + 3);
    }
    hl4[wv][slotW] = make_float4(loF(p0), loF(p1), loF(p2), loF(p3));

    // ---- h-MAC: 4 gates x 32 h (same accumulation order) ----
#pragma unroll
    for (int q = 0; q < 8; ++q) {
      const float4 hv = hl4[wv][kcL * 8 + (q ^ kcL)];   // logical local granule kcL*8+q
      const int b = q * 4;
      a0.x += wh[0][b + 0] * hv.x; a0.y += wh[0][b + 1] * hv.y; a0.z += wh[0][b + 2] * hv.z; a0.w += wh[0][b + 3] * hv.w;
      a1.x += wh[1][b + 0] * hv.x; a1.y += wh[1][b + 1] * hv.y; a1.z += wh[1][b + 2] * hv.z; a1.w += wh[1][b + 3] * hv.w;
      a2.x += wh[2][b + 0] * hv.x; a2.y += wh[2][b + 1] * hv.y; a2.z += wh[2][b + 2] * hv.z; a2.w += wh[2][b + 3] * hv.w;
      a3.x += wh[3][b + 0] * hv.x; a3.y += wh[3][b + 1] * hv.y; a3.z += wh[3][b + 2] * hv.z; a3.w += wh[3][b + 3] * hv.w;
    }

    float r0 = (a0.x + a0.y) + (a0.z + a0.w);
    float r1 = (a1.x + a1.y) + (a1.z + a1.w);
    float r2 = (a2.x + a2.y) + (a2.z + a2.w);
    float r3 = (a3.x + a3.y) + (a3.z + a3.w);
#pragma unroll
    for (int m = 8; m < 64; m <<= 1) {
      r0 += __shfl_xor(r0, m); r1 += __shfl_xor(r1, m);
      r2 += __shfl_xor(r2, m); r3 += __shfl_xor(r3, m);
    }
    if (lane < 8) *(float4*)&partbuf[par][wv][lane][0] = make_float4(r0, r1, r2, r3);

    // ---- last-arriving wave: activation + single-instruction 64-lane mirrored fan-out ----
    unsigned rt = 0u;
    if (lane == 0)
      rt = __hip_atomic_fetch_add(&cnt[par], 1u, __ATOMIC_ACQ_REL, __HIP_MEMORY_SCOPE_WORKGROUP);
    rt = __shfl(rt, 0);
    if (rt == 7u) {
      __builtin_amdgcn_s_setprio(1);
      if (lane == 0)
        __hip_atomic_store(&cnt[par], 0u, __ATOMIC_RELAXED, __HIP_MEMORY_SCOPE_WORKGROUP);
      float hN = 0.0f;
      if (lane < 8) {
        float s0 = 0.f, s1 = 0.f, s2 = 0.f, s3 = 0.f;
#pragma unroll
        for (int w = 0; w < 8; ++w) {   // fixed order: bit-exact vs r8
          const float4 pv = *(const float4*)&partbuf[par][w][lane][0];
          s0 += pv.x; s1 += pv.y; s2 += pv.z; s3 += pv.w;
        }
        const float gi = s0 + bi0, gf = s1 + bi1;
        const float gg = s2 + bi2, go = s3 + bi3;
        const float cN = sigf(gf) * c_s[lane] + sigf(gi) * tanhf(gg);
        c_s[lane] = cN;
        hN = sigf(go) * tanhf(cN);
      }
      asm volatile("s_waitcnt lgkmcnt(0)" ::: "memory");  // cnt reset + c_s retired
      if (t + 1 == SEQ) {
        if (lane < 8) hencbuf[jbase + lane] = hN;   // plain; flushed at kernel end
      } else {
        const float hNb = __shfl(hN, lane & 7);     // lane -> (mirror lane>>3, j lane&7)
        u64t* hb = hbuf + (size_t)(1 - par) * (NMIR * 2048)
                        + (size_t)(lane >> 3) * 2048 + jbase + (lane & 7);
        AST(hb, packFT(hNb, tt + 1));               // one store instr, 8 mirror lines
      }
      __builtin_amdgcn_s_setprio(0);
    }
  }
}

// ---------------- persistent decoder (r8 + biases in pinned registers) ----------------
// 16 WGs x 512 thr. WG w owns c-indices [32w,32w+32). Thread: j=tid&31, kc=tid>>5.
// Wave wv consumes hraw floats [60wv..60wv+60) as tagged u64.
__global__ __launch_bounds__(512) __attribute__((amdgpu_waves_per_eu(2, 2))) void dec_kernel(
    const float* __restrict__ dWih, const float* __restrict__ Wfold,
    const float* __restrict__ btot, const float* __restrict__ henc,
    u64t* __restrict__ hraw, float* __restrict__ out) {
  const int tid  = threadIdx.x;
  const int wg   = blockIdx.x;
  const int j    = tid & 31;
  const int kc   = tid >> 5;   // 0..15
  const int wv   = tid >> 6;   // 0..7
  const int lane = tid & 63;
  const int kcL  = kc & 1;
  const int idx = wg * 32 + j;
  const bool valid = (idx < INP);
  const int id0 = valid ? idx : 0;

  float wd[4][30];
#pragma unroll
  for (int g = 0; g < 4; ++g) {
    const float* wp = Wfold + (size_t)(g * INP + id0) * 480 + kc * 30;
#pragma unroll
    for (int q = 0; q < 15; ++q) {
      const float2 v = valid ? *(const float2*)(wp + 2 * q) : make_float2(0.0f, 0.0f);
      wd[g][q * 2 + 0] = v.x; wd[g][q * 2 + 1] = v.y;
    }
  }
#pragma unroll
  for (int g = 0; g < 4; ++g)
#pragma unroll
    for (int q = 0; q < 30; ++q) PIN(wd[g][q]);

  // gate biases in registers (act path, lane<32)
  const int jb32 = lane & 31;
  const int ixb  = wg * 32 + jb32;
  const bool vb  = (ixb < INP);
  float di0 = vb ? btot[0 * INP + ixb] : 0.0f;
  float di1 = vb ? btot[1 * INP + ixb] : 0.0f;
  float di2 = vb ? btot[2 * INP + ixb] : 0.0f;
  float di3 = vb ? btot[3 * INP + ixb] : 0.0f;
  PIN(di0); PIN(di1); PIN(di2); PIN(di3);

  __shared__ float dl[8][60];              // per-wave staged hraw slice
  __shared__ float partbuf[2][8][32][4];   // parity x wave x j x gate
  __shared__ float c_s[32];
  __shared__ unsigned cnt[2];
  if (tid < 32) c_s[tid] = 0.0f;
  if (tid < 2)  cnt[tid] = 0u;
  __syncthreads();   // only barrier

  for (int t = 0; t < SEQ; ++t) {
    const unsigned tt = (unsigned)t;
    const int par = t & 1;

    if (t > 0) {
      // direct tagged stage: wave wv needs floats [60wv..60wv+60)
      if (lane < 60) {
        const int fidx = wv * 60 + lane;
        float v = 0.0f;
        if (fidx < INP) {
          const u64t* hp = hraw + (size_t)par * 512 + fidx;
          u64t p = ALD(hp);
          while (hiT(p) < tt) p = ALD(hp);
          v = loF(p);
        }
        dl[wv][lane] = v;
      }
    }

    float2 acc0 = make_float2(0, 0), acc1 = acc0, acc2 = acc0, acc3 = acc0;
    if (t == 0) {
      if (valid) {
#pragma unroll 4
        for (int q = 0; q < 32; ++q) {
          const float4 hv = *(const float4*)(henc + kc * 128 + 4 * q);
          const float4 w0 = *(const float4*)(dWih + (size_t)(0 * INP + idx) * EMB + kc * 128 + 4 * q);
          const float4 w1 = *(const float4*)(dWih + (size_t)(1 * INP + idx) * EMB + kc * 128 + 4 * q);
          const float4 w2 = *(const float4*)(dWih + (size_t)(2 * INP + idx) * EMB + kc * 128 + 4 * q);
          const float4 w3 = *(const float4*)(dWih + (size_t)(3 * INP + idx) * EMB + kc * 128 + 4 * q);
          acc0.x += w0.x * hv.x + w0.z * hv.z; acc0.y += w0.y * hv.y + w0.w * hv.w;
          acc1.x += w1.x * hv.x + w1.z * hv.z; acc1.y += w1.y * hv.y + w1.w * hv.w;
          acc2.x += w2.x * hv.x + w2.z * hv.z; acc2.y += w2.y * hv.y + w2.w * hv.w;
          acc3.x += w3.x * hv.x + w3.z * hv.z; acc3.y += w3.y * hv.y + w3.w * hv.w;
        }
      }
    } else {
#pragma unroll
      for (int q = 0; q < 15; ++q) {
        const float2 hv = *(const float2*)&dl[wv][kcL * 30 + 2 * q];
        acc0.x += wd[0][q * 2] * hv.x; acc0.y += wd[0][q * 2 + 1] * hv.y;
        acc1.x += wd[1][q * 2] * hv.x; acc1.y += wd[1][q * 2 + 1] * hv.y;
        acc2.x += wd[2][q * 2] * hv.x; acc2.y += wd[2][q * 2 + 1] * hv.y;
        acc3.x += wd[3][q * 2] * hv.x; acc3.y += wd[3][q * 2 + 1] * hv.y;
      }
    }
    float r0 = acc0.x + acc0.y, r1 = acc1.x + acc1.y, r2 = acc2.x + acc2.y, r3 = acc3.x + acc3.y;
    r0 += __shfl_xor(r0, 32); r1 += __shfl_xor(r1, 32);
    r2 += __shfl_xor(r2, 32); r3 += __shfl_xor(r3, 32);
    if (lane < 32) *(float4*)&partbuf[par][wv][lane][0] = make_float4(r0, r1, r2, r3);

    unsigned rt = 0u;
    if (lane == 0)
      rt = __hip_atomic_fetch_add(&cnt[par], 1u, __ATOMIC_ACQ_REL, __HIP_MEMORY_SCOPE_WORKGROUP);
    rt = __shfl(rt, 0);
    if (rt == 7u) {
      __builtin_amdgcn_s_setprio(1);
      if (lane == 0)
        __hip_atomic_store(&cnt[par], 0u, __ATOMIC_RELAXED, __HIP_MEMORY_SCOPE_WORKGROUP);
      if (lane < 32) {
        float s0 = 0.f, s1 = 0.f, s2 = 0.f, s3 = 0.f;
#pragma unroll
        for (int w = 0; w < 8; ++w) {
          const float4 pv = *(const float4*)&partbuf[par][w][lane][0];
          s0 += pv.x; s1 += pv.y; s2 += pv.z; s3 += pv.w;
        }
        const float gi = s0 + di0, gf = s1 + di1;
        const float gg = s2 + di2, go = s3 + di3;
        const float cN = sigf(gf) * c_s[lane] + sigf(gi) * tanhf(gg);
        c_s[lane] = cN;
        asm volatile("s_waitcnt lgkmcnt(0)" ::: "memory");
        const int ix = wg * 32 + lane;
        if (ix < INP) {
          out[(size_t)(SEQ - 1 - t) * INP + ix] = cN;
          if (t + 1 < SEQ) {
            const float hrN = sigf(go) * tanhf(cN);
            AST(hraw + (size_t)(1 - par) * 512 + ix, packFT(hrN, tt + 1));
          }
        }
      }
      __builtin_amdgcn_s_setprio(0);
    }
  }
}

// ---------------- row softmax in-place on d_out (4096 x 457) ----------------
__global__ __launch_bounds__(512) void softmax_kernel(float* __restrict__ out) {
  const int row = blockIdx.x;
  const int tid = threadIdx.x;
  __shared__ float red[512];
  float* rp = out + (size_t)row * INP;
  float v = (tid < INP) ? rp[tid] : -INFINITY;
  red[tid] = v;
  __syncthreads();
#pragma unroll
  for (int off = 256; off > 0; off >>= 1) {
    if (tid < off) red[tid] = fmaxf(red[tid], red[tid + off]);
    __syncthreads();
  }
  const float m = red[0];
  __syncthreads();
  const float e = (tid < INP) ? expf(v - m) : 0.0f;
  red[tid] = e;
  __syncthreads();
#pragma unroll
  for (int off = 256; off > 0; off >>= 1) {
    if (tid < off) red[tid] = red[tid] + red[tid + off];
    __syncthreads();
  }
  const float s = red[0];
  if (tid < INP) rp[tid] = e / s;
}

extern "C" void kernel_launch(void* const* d_in, const int* in_sizes, int n_in,
                              void* d_out, int out_size, void* d_ws, size_t ws_size,
                              hipStream_t stream) {
  const float* x    = (const float*)d_in[0];
  const float* eWih = (const float*)d_in[1];
  const float* eWhh = (const float*)d_in[2];
  const float* ebih = (const float*)d_in[3];
  const float* ebhh = (const float*)d_in[4];
  const float* dWih = (const float*)d_in[5];
  const float* dWhh = (const float*)d_in[6];
  const float* dbih = (const float*)d_in[7];
  const float* dbhh = (const float*)d_in[8];
  const float* dWhr = (const float*)d_in[9];
  float* out = (float*)d_out;
  char* ws = (char*)d_ws;

  // ws layout:
  // [4096,266240):     hbuf u64[2][NMIR][2048] (tagged h, 8 mirrors; zero => val 0, tag 0)
  // [266240,274432):   hraw u64[2][512]   (tagged decoder h_raw, single copy)
  // [274432,282624):   hencbuf f32[2048]  (plain final encoder h for dec t==0)
  // [282624,315392):   bsum f32[8192]
  // [315392,323584):   btot
  // [327680,+3.51MB):  Wfold 1828x480
  u64t* hbuf   = (u64t*)(ws + 4096);
  u64t* hraw   = (u64t*)(ws + 266240);
  float* hencb = (float*)(ws + 274432);
  float* bsum  = (float*)(ws + 282624);
  float* btot  = (float*)(ws + 315392);
  float* Wfold = (float*)(ws + 327680);

  hipMemsetAsync(ws, 0, 274432, stream);  // hbuf (all mirrors) + hraw (tags=0, vals=0)
  bias_kernel<<<40, 256, 0, stream>>>(ebih, ebhh, dbih, dbhh, bsum, btot);
  fold_gemm<<<dim3(8, 29), 256, 0, stream>>>(dWih, dWhh, dWhr, Wfold);
  enc_kernel<<<NWG_E, 512, 0, stream>>>(x, eWih, eWhh, bsum, hbuf, hencb);
  dec_kernel<<<NWG_D, 512, 0, stream>>>(dWih, Wfold, btot, hencb, hraw, out);
  softmax_kernel<<<SEQ, 512, 0, stream>>>(out);
}